// Round 3
// baseline (292.497 us; speedup 1.0000x reference)
//
#include <hip/hip_runtime.h>
#include <hip/hip_bf16.h>

#define NB 4
#define NS 2048
#define NE 128
#define NH 16
#define ND 8

// Kernel 1: per (b,h): attn = softmax(q q^T / sqrt(8)) @ q, where
//   q[s][d] = cumprod_{i<=d} cos(x[b][s][h*8+i] + theta[i])
// grid = (B*H, S/256); block = 256; each thread owns one query row.
// q for the whole (b,h) slice is computed into LDS (fp32, 64 KB).
// |q| <= 1 so |score| <= 8/sqrt(8) = 2.83 -> softmax needs no max-subtract.
// Writes the attention result (fp32, [B][S][E] layout) to `attn` (= d_ws).
__global__ __launch_bounds__(256) void attn_kernel(
        const float* __restrict__ x,
        const float* __restrict__ theta,
        const int* __restrict__ mask,
        float* __restrict__ attn) {
    __shared__ float kv[NS * ND];   // 64 KB
    __shared__ float km[NS];        // 8 KB
    int bh = blockIdx.x;            // 0..63
    int tile = blockIdx.y;          // 0..7
    int b = bh >> 4;
    int h = bh & (NH - 1);
    int tid = threadIdx.x;

    float th[ND];
#pragma unroll
    for (int d = 0; d < ND; d++) th[d] = theta[d];

    // stage q rows for this (b,h): 8 rows per thread
    for (int i = tid; i < NS; i += 256) {
        const float* xp = x + ((size_t)(b * NS + i) * NE + h * ND);
        float4 x0 = *reinterpret_cast<const float4*>(xp);
        float4 x1 = *reinterpret_cast<const float4*>(xp + 4);
        float p = 1.0f;
        float* kvp = &kv[i * ND];
        p *= cosf(x0.x + th[0]); kvp[0] = p;
        p *= cosf(x0.y + th[1]); kvp[1] = p;
        p *= cosf(x0.z + th[2]); kvp[2] = p;
        p *= cosf(x0.w + th[3]); kvp[3] = p;
        p *= cosf(x1.x + th[4]); kvp[4] = p;
        p *= cosf(x1.y + th[5]); kvp[5] = p;
        p *= cosf(x1.z + th[6]); kvp[6] = p;
        p *= cosf(x1.w + th[7]); kvp[7] = p;
    }
    for (int i = tid; i < NS; i += 256)
        km[i] = mask[b * NS + i] ? 1.0f : 0.0f;
    __syncthreads();

    int s = tile * 256 + tid;
    float qr[ND];
#pragma unroll
    for (int d = 0; d < ND; d++) qr[d] = kv[s * ND + d];

    const float scale = 0.35355339059327373f;   // 1/sqrt(8)
    float acc[ND] = {0.f, 0.f, 0.f, 0.f, 0.f, 0.f, 0.f, 0.f};
    float l = 0.f;
    for (int t = 0; t < NS; t++) {
        float4 k0 = *reinterpret_cast<const float4*>(&kv[t * ND]);
        float4 k1 = *reinterpret_cast<const float4*>(&kv[t * ND + 4]);
        float dot = qr[0] * k0.x + qr[1] * k0.y + qr[2] * k0.z + qr[3] * k0.w
                  + qr[4] * k1.x + qr[5] * k1.y + qr[6] * k1.z + qr[7] * k1.w;
        float e = __expf(dot * scale) * km[t];
        l += e;
        acc[0] += e * k0.x; acc[1] += e * k0.y; acc[2] += e * k0.z; acc[3] += e * k0.w;
        acc[4] += e * k1.x; acc[5] += e * k1.y; acc[6] += e * k1.z; acc[7] += e * k1.w;
    }
    float inv = 1.0f / l;
    float* ap = attn + ((size_t)(b * NS + s) * NE + h * ND);
    *reinterpret_cast<float4*>(ap)     = make_float4(acc[0] * inv, acc[1] * inv, acc[2] * inv, acc[3] * inv);
    *reinterpret_cast<float4*>(ap + 4) = make_float4(acc[4] * inv, acc[5] * inv, acc[6] * inv, acc[7] * inv);
}

// Kernel 2: out[r][e] = sum_j mid[r][j] * w_out[e][j]   (attn @ w_out^T)
// Pure: reads mid (= d_ws), writes out (= d_out). No in-place anything.
// grid = B*S/2; block = 256 (2 rows x 128 outputs).
__global__ __launch_bounds__(256) void proj_kernel(
        const float* __restrict__ mid,
        const float* __restrict__ w,
        float* __restrict__ out) {
    __shared__ float a[2][NE];
    int row0 = blockIdx.x * 2;
    int tid = threadIdx.x;
    int r = tid >> 7;       // 0 or 1
    int e = tid & (NE - 1);
    a[r][e] = mid[(size_t)(row0 + r) * NE + e];
    __syncthreads();
    const float* wp = w + (size_t)e * NE;
    float acc = 0.f;
#pragma unroll
    for (int j = 0; j < NE; j += 4) {
        float4 rw = *reinterpret_cast<const float4*>(wp + j);
        acc += a[r][j]     * rw.x;
        acc += a[r][j + 1] * rw.y;
        acc += a[r][j + 2] * rw.z;
        acc += a[r][j + 3] * rw.w;
    }
    out[(size_t)(row0 + r) * NE + e] = acc;
}

extern "C" void kernel_launch(void* const* d_in, const int* in_sizes, int n_in,
                              void* d_out, int out_size, void* d_ws, size_t ws_size,
                              hipStream_t stream) {
    const float* x     = (const float*)d_in[0];
    const float* theta = (const float*)d_in[1];
    const float* w_out = (const float*)d_in[2];
    const int*   mask  = (const int*)d_in[3];
    float* out = (float*)d_out;

    // Intermediate attention result [B][S][E] fp32 = 4 MB lives in d_ws so
    // kernel_launch is a pure function of d_in (never reads d_out/d_ws state).
    const size_t mid_bytes = (size_t)NB * NS * NE * sizeof(float);
    float* mid = (ws_size >= mid_bytes) ? (float*)d_ws : out;

    attn_kernel<<<dim3(NB * NH, NS / 256), 256, 0, stream>>>(x, theta, mask, mid);
    proj_kernel<<<NB * NS / 2, 256, 0, stream>>>(mid, w_out, out);
}

// Round 4
// 151.153 us; speedup vs baseline: 1.9351x; 1.9351x over previous
//
#include <hip/hip_runtime.h>
#include <hip/hip_bf16.h>

#define NB 4
#define NS 2048
#define NE 128
#define NH 16
#define ND 8

typedef __attribute__((ext_vector_type(8))) short short8;
typedef __attribute__((ext_vector_type(4))) float f32x4;

__device__ __forceinline__ unsigned short f2bf(float f) {
    unsigned u = __float_as_uint(f);
    u = (u + 0x7FFFu + ((u >> 16) & 1u)) >> 16;   // RNE
    return (unsigned short)u;
}
__device__ __forceinline__ float bf2f(unsigned short s) {
    return __uint_as_float(((unsigned)s) << 16);
}

#define QSTRIDE 16      // shorts per qhl row: [hi x8 | lo x8] = 32 B
#define VSTRIDE 2064    // shorts per vT row (2048 + 16 pad)
#define PSTRIDE 20      // uints per P row = 80 B (pad vs 64 to break banks)

// One block = one (b,h) and one quarter of the query rows (512 rows).
// 1024 threads = 16 waves; each wave owns 2 m-tiles of 16 rows.
// Flash loop over 64 chunks of 32 t. Scores: mfma 16x16x32 bf16 with hi/lo
// split (K slots A=[hi|hi|lo|0], B=[hi|lo|hi|0]) -> fp32-quality q.q^T/sqrt(8)
// (scale 8^-1/4 folded into both operands). Softmax single-pass (|s|<=2.83).
// P -> A-layout via per-wave LDS roundtrip; V^T staged chunk-interleaved so
// its B-frag k-order matches P's packed k-order.
__global__ __launch_bounds__(1024) void attn_kernel(
        const float* __restrict__ x,
        const float* __restrict__ theta,
        const int* __restrict__ mask,
        float* __restrict__ mid) {
    __shared__ unsigned short qhl[2049 * QSTRIDE];    // 65,568 B (row 2048 = zeros)
    __shared__ unsigned short vT[ND * VSTRIDE];       // 33,024 B
    __shared__ unsigned int   Pu[16 * 16 * PSTRIDE];  // 20,480 B (per-wave scratch)

    const int bid = blockIdx.x;
    const int bh = bid >> 2;
    const int b = bh >> 4, h = bh & (NH - 1);
    const int mquart = bid & 3;
    const int tid = threadIdx.x;

    float th[ND];
#pragma unroll
    for (int d = 0; d < ND; d++) th[d] = theta[d];

    const float S4 = 0.59460355750136051f;  // 8^(-1/4); S4*S4 = 1/sqrt(8)

    // ---- stage q rows for the whole (b,h): 2 rows per thread ----
#pragma unroll
    for (int rr = 0; rr < 2; rr++) {
        int t = tid + rr * 1024;
        const float* xp = x + ((size_t)(b * NS + t) * NE + h * ND);
        float4 x0 = *(const float4*)xp;
        float4 x1 = *(const float4*)(xp + 4);
        float p[ND];
        float c = 1.f;
        c *= cosf(x0.x + th[0]); p[0] = c;
        c *= cosf(x0.y + th[1]); p[1] = c;
        c *= cosf(x0.z + th[2]); p[2] = c;
        c *= cosf(x0.w + th[3]); p[3] = c;
        c *= cosf(x1.x + th[4]); p[4] = c;
        c *= cosf(x1.y + th[5]); p[5] = c;
        c *= cosf(x1.z + th[6]); p[6] = c;
        c *= cosf(x1.w + th[7]); p[7] = c;

        unsigned hi[ND], lo[ND];
#pragma unroll
        for (int d = 0; d < ND; d++) {
            float qs = p[d] * S4;
            hi[d] = f2bf(qs);
            lo[d] = f2bf(qs - bf2f((unsigned short)hi[d]));
        }
        uint4 hv, lv;
        hv.x = hi[0] | (hi[1] << 16); hv.y = hi[2] | (hi[3] << 16);
        hv.z = hi[4] | (hi[5] << 16); hv.w = hi[6] | (hi[7] << 16);
        lv.x = lo[0] | (lo[1] << 16); lv.y = lo[2] | (lo[3] << 16);
        lv.z = lo[4] | (lo[5] << 16); lv.w = lo[6] | (lo[7] << 16);
        *(uint4*)&qhl[t * QSTRIDE]     = hv;
        *(uint4*)&qhl[t * QSTRIDE + 8] = lv;

        // V^T (unscaled), chunk-interleaved: c = 2*(tl&15) + (tl>>4)
        int tl = t & 31, ch = t >> 5;
        int kt = 2 * (tl & 15) + (tl >> 4);
#pragma unroll
        for (int d = 0; d < ND; d++)
            vT[d * VSTRIDE + ch * 32 + kt] = f2bf(p[d]);
    }
    if (tid < QSTRIDE) qhl[2048 * QSTRIDE + tid] = 0;   // zero row for quad-3 frags
    __syncthreads();

    // ---- main flash loop ----
    const int wave = tid >> 6, lane = tid & 63;
    const int quad = lane >> 4, l15 = lane & 15;
    const int mbase = mquart * 512 + wave * 32;

    short8 afrag[2];
#pragma unroll
    for (int mt = 0; mt < 2; mt++) {
        int rowA = (quad == 3) ? 2048 : (mbase + mt * 16 + l15);
        int offA = (quad == 2) ? 8 : 0;            // A k-slots: hi,hi,lo,0
        afrag[mt] = *(const short8*)&qhl[rowA * QSTRIDE + offA];
    }
    f32x4 O[2]   = {{0.f,0.f,0.f,0.f},{0.f,0.f,0.f,0.f}};
    f32x4 lac[2] = {{0.f,0.f,0.f,0.f},{0.f,0.f,0.f,0.f}};
    unsigned int* Pw = Pu + wave * (16 * PSTRIDE);
    const int offB = (quad == 1) ? 8 : 0;          // B k-slots: hi,lo,hi,0
    const int* mrow = mask + b * NS;

    for (int ch = 0; ch < 64; ch++) {
        short8 bfrag[2];
#pragma unroll
        for (int tt = 0; tt < 2; tt++) {
            int rowB = (quad == 3) ? 2048 : (ch * 32 + tt * 16 + l15);
            bfrag[tt] = *(const short8*)&qhl[rowB * QSTRIDE + offB];
        }
        short8 vfrag = *(const short8*)&vT[(l15 & 7) * VSTRIDE + ch * 32 + quad * 8];
        float km0 = mrow[ch * 32 + l15]      ? 1.f : 0.f;
        float km1 = mrow[ch * 32 + 16 + l15] ? 1.f : 0.f;

#pragma unroll
        for (int mt = 0; mt < 2; mt++) {
            f32x4 z = {0.f, 0.f, 0.f, 0.f};
            f32x4 c0 = __builtin_amdgcn_mfma_f32_16x16x32_bf16(afrag[mt], bfrag[0], z, 0, 0, 0);
            f32x4 c1 = __builtin_amdgcn_mfma_f32_16x16x32_bf16(afrag[mt], bfrag[1], z, 0, 0, 0);
#pragma unroll
            for (int r = 0; r < 4; r++) {
                float e0 = __expf(c0[r]) * km0;
                float e1 = __expf(c1[r]) * km1;
                lac[mt][r] += e0 + e1;
                // C-layout value (m=quad*4+r, t=tt*16+l15) -> packed col c=2*l15+tt
                Pw[(quad * 4 + r) * PSTRIDE + l15] =
                    (unsigned)f2bf(e0) | ((unsigned)f2bf(e1) << 16);
            }
            __asm__ volatile("" ::: "memory");   // pin write->read order for compiler
            short8 pf = *(const short8*)((const unsigned short*)Pw
                                         + l15 * (PSTRIDE * 2) + quad * 8);
            O[mt] = __builtin_amdgcn_mfma_f32_16x16x32_bf16(pf, vfrag, O[mt], 0, 0, 0);
            __asm__ volatile("" ::: "memory");   // keep next iter's writes after read
        }
    }

    // ---- finalize: reduce l over the 16-lane dim, scale, write ----
#pragma unroll
    for (int mt = 0; mt < 2; mt++) {
#pragma unroll
        for (int r = 0; r < 4; r++) {
            float v = lac[mt][r];
            v += __shfl_xor(v, 1); v += __shfl_xor(v, 2);
            v += __shfl_xor(v, 4); v += __shfl_xor(v, 8);
            float inv = 1.0f / v;
            if (l15 < ND) {
                int m = mbase + mt * 16 + quad * 4 + r;
                mid[(size_t)(b * NS + m) * NE + h * ND + l15] = O[mt][r] * inv;
            }
        }
    }
}

// w^T[j][e] = w[e][j]  (64 KB, one-time per launch)
__global__ __launch_bounds__(256) void wt_kernel(
        const float* __restrict__ w, float* __restrict__ wT) {
    int id = blockIdx.x * 256 + threadIdx.x;   // 16384
    int e = id >> 7, j = id & 127;
    wT[j * NE + e] = w[e * NE + j];
}

// out[r][e] = sum_j mid[r][j] * wT[j][e] — fully coalesced wT reads.
__global__ __launch_bounds__(256) void proj_kernel(
        const float* __restrict__ mid, const float* __restrict__ wT,
        float* __restrict__ out) {
    __shared__ float a[16][132];   // +4 pad: conflict-free a[rs][j] reads
    int rb = blockIdx.x * 16;
    int tid = threadIdx.x;
#pragma unroll
    for (int k = 0; k < 2; k++) {
        int idx = k * 256 + tid;            // coalesced: lanes consecutive
        int row = idx >> 5, c4 = idx & 31;
        *(float4*)&a[row][c4 * 4] =
            *(const float4*)&mid[(size_t)(rb + row) * NE + c4 * 4];
    }
    __syncthreads();
    int eq = tid & 31, rs = tid >> 5;       // e = eq*4; rows rs, rs+8
    float4 acc0 = {0,0,0,0}, acc1 = {0,0,0,0};
#pragma unroll 4
    for (int j = 0; j < NE; j++) {
        float4 wv = *(const float4*)&wT[j * NE + eq * 4];
        float a0 = a[rs][j], a1 = a[rs + 8][j];
        acc0.x += a0 * wv.x; acc0.y += a0 * wv.y;
        acc0.z += a0 * wv.z; acc0.w += a0 * wv.w;
        acc1.x += a1 * wv.x; acc1.y += a1 * wv.y;
        acc1.z += a1 * wv.z; acc1.w += a1 * wv.w;
    }
    *(float4*)&out[(size_t)(rb + rs) * NE + eq * 4]     = acc0;
    *(float4*)&out[(size_t)(rb + rs + 8) * NE + eq * 4] = acc1;
}

// Fallback proj (reads w directly) if ws has room for mid but not wT.
__global__ __launch_bounds__(256) void proj_slow_kernel(
        const float* __restrict__ mid, const float* __restrict__ w,
        float* __restrict__ out) {
    __shared__ float a[2][NE];
    int row0 = blockIdx.x * 2;
    int tid = threadIdx.x;
    int r = tid >> 7, e = tid & (NE - 1);
    a[r][e] = mid[(size_t)(row0 + r) * NE + e];
    __syncthreads();
    const float* wp = w + (size_t)e * NE;
    float acc = 0.f;
#pragma unroll
    for (int j = 0; j < NE; j += 4) {
        float4 rw = *(const float4*)(wp + j);
        acc += a[r][j] * rw.x + a[r][j+1] * rw.y + a[r][j+2] * rw.z + a[r][j+3] * rw.w;
    }
    out[(size_t)(row0 + r) * NE + e] = acc;
}

extern "C" void kernel_launch(void* const* d_in, const int* in_sizes, int n_in,
                              void* d_out, int out_size, void* d_ws, size_t ws_size,
                              hipStream_t stream) {
    const float* x     = (const float*)d_in[0];
    const float* theta = (const float*)d_in[1];
    const float* w_out = (const float*)d_in[2];
    const int*   mask  = (const int*)d_in[3];
    float* out = (float*)d_out;

    const size_t mid_elems = (size_t)NB * NS * NE;           // 1M floats = 4 MB
    const size_t need_fast = (mid_elems + NE * NE) * 4;      // + 64 KB wT
    float* mid = (float*)d_ws;
    float* wT  = mid + mid_elems;

    attn_kernel<<<NB * NH * 4, 1024, 0, stream>>>(x, theta, mask, mid);
    if (ws_size >= need_fast) {
        wt_kernel<<<NE * NE / 256, 256, 0, stream>>>(w_out, wT);
        proj_kernel<<<NB * NS / 16, 256, 0, stream>>>(mid, wT, out);
    } else {
        proj_slow_kernel<<<NB * NS / 2, 256, 0, stream>>>(mid, w_out, out);
    }
}

// Round 7
// 112.807 us; speedup vs baseline: 2.5929x; 1.3399x over previous
//
#include <hip/hip_runtime.h>
#include <hip/hip_bf16.h>
#include <hip/hip_fp16.h>

#define NB 4
#define NS 2048
#define NE 128
#define NH 16
#define ND 8

typedef __attribute__((ext_vector_type(8))) _Float16 half8;
typedef __attribute__((ext_vector_type(4))) float f32x4;

#define VSTRIDE 2056   // shorts per vT row (2048 + 8 pad -> banks d*4, conflict-free)
#define PSTRIDE 18     // uints per P row (odd*2 -> <=2-way banks, 8B-aligned b64 reads)

__device__ __forceinline__ unsigned int pkrtz(float a, float b) {
    typedef __fp16 fp16v2 __attribute__((ext_vector_type(2)));
    union { fp16v2 h; unsigned int u; } v;
    v.h = __builtin_amdgcn_cvt_pkrtz(a, b);
    return v.u;
}
__device__ __forceinline__ unsigned short f2h(float a) {
    return __half_as_ushort(__float2half(a));   // RNE
}
// Read P as the SAME type it was written with (unsigned int) — TBAA-safe;
// compiler merges the 4 consecutive uints into 2x ds_read_b64 (8B-aligned).
__device__ __forceinline__ half8 ld_p(const unsigned int* p) {
    union { half8 s; unsigned int u[4]; } v;
    v.u[0] = p[0]; v.u[1] = p[1]; v.u[2] = p[2]; v.u[3] = p[3];
    return v.s;
}

// One block = one (b,h) x one quarter of query rows. 1024 thr = 16 waves,
// each wave owns 2 m-tiles of 16 rows. Flash loop over 64 chunks of 32 t.
// q scaled by SC = sqrt(log2e/sqrt(8)) so scores come out in exp2 domain:
// e = v_exp_f32(score) directly. Mask enters as the MFMA C operand (0/-30000).
// P -> f16 via cvt_pkrtz, per-wave LDS roundtrip to A-layout (fenced! the
// write->read order through LDS must be pinned or the compiler hoists the
// reads — that was R6's bug). V^T has a ones row at n=8, so PV's output
// column 8 is the softmax denominator for free.
__global__ __launch_bounds__(1024) void attn_kernel(
        const float* __restrict__ x,
        const float* __restrict__ theta,
        const int* __restrict__ mask,
        unsigned short* __restrict__ mid) {            // f16 [B*S][NE]
    __shared__ unsigned short qhl[NS * ND];            // 32768 B: f16 q*SC
    __shared__ unsigned short vT[9 * VSTRIDE];         // 37008 B: f16 V^T + ones row
    __shared__ unsigned int   Pu[16 * 2 * 16 * PSTRIDE]; // 36864 B: per-wave/mt P

    const int bid = blockIdx.x;
    const int bh = bid >> 2;
    const int b = bh >> 4, h = bh & (NH - 1);
    const int mquart = bid & 3;
    const int tid = threadIdx.x;

    const float SC = 0.71421629f;   // sqrt(log2(e)/sqrt(8))

    float th[ND];
#pragma unroll
    for (int d = 0; d < ND; d++) th[d] = theta[d];

    // ---- stage: thread handles rows t0 = ch*32+i, t1 = t0+16 (ch=tid>>4,i=tid&15)
    {
        int ch = tid >> 4, i = tid & 15;
        int t0 = ch * 32 + i, t1 = t0 + 16;
        float p0[ND], p1[ND];
        {
            const float* xp = x + ((size_t)(b * NS + t0) * NE + h * ND);
            float4 a = *(const float4*)xp, c = *(const float4*)(xp + 4);
            float p = 1.f;
            p *= cosf(a.x + th[0]); p0[0] = p; p *= cosf(a.y + th[1]); p0[1] = p;
            p *= cosf(a.z + th[2]); p0[2] = p; p *= cosf(a.w + th[3]); p0[3] = p;
            p *= cosf(c.x + th[4]); p0[4] = p; p *= cosf(c.y + th[5]); p0[5] = p;
            p *= cosf(c.z + th[6]); p0[6] = p; p *= cosf(c.w + th[7]); p0[7] = p;
        }
        {
            const float* xp = x + ((size_t)(b * NS + t1) * NE + h * ND);
            float4 a = *(const float4*)xp, c = *(const float4*)(xp + 4);
            float p = 1.f;
            p *= cosf(a.x + th[0]); p1[0] = p; p *= cosf(a.y + th[1]); p1[1] = p;
            p *= cosf(a.z + th[2]); p1[2] = p; p *= cosf(a.w + th[3]); p1[3] = p;
            p *= cosf(c.x + th[4]); p1[4] = p; p *= cosf(c.y + th[5]); p1[5] = p;
            p *= cosf(c.z + th[6]); p1[6] = p; p *= cosf(c.w + th[7]); p1[7] = p;
        }
        uint4 qa, qb;
        qa.x = pkrtz(p0[0] * SC, p0[1] * SC);
        qa.y = pkrtz(p0[2] * SC, p0[3] * SC);
        qa.z = pkrtz(p0[4] * SC, p0[5] * SC);
        qa.w = pkrtz(p0[6] * SC, p0[7] * SC);
        qb.x = pkrtz(p1[0] * SC, p1[1] * SC);
        qb.y = pkrtz(p1[2] * SC, p1[3] * SC);
        qb.z = pkrtz(p1[4] * SC, p1[5] * SC);
        qb.w = pkrtz(p1[6] * SC, p1[7] * SC);
        *(uint4*)&qhl[t0 * ND] = qa;
        *(uint4*)&qhl[t1 * ND] = qb;
        // V^T, k-interleaved: uint at [d][ch*32+2i] = (V[t0][d], V[t1][d])
#pragma unroll
        for (int d = 0; d < ND; d++)
            *(unsigned int*)&vT[d * VSTRIDE + ch * 32 + 2 * i] = pkrtz(p0[d], p1[d]);
        *(unsigned int*)&vT[8 * VSTRIDE + ch * 32 + 2 * i] = 0x3C003C00u;  // ones
    }
    __syncthreads();

    // ---- main loop ----
    const int wave = tid >> 6, lane = tid & 63;
    const int quad = lane >> 4, l15 = lane & 15;
    const int mbase = mquart * 512 + wave * 32;

    half8 hz = {0, 0, 0, 0, 0, 0, 0, 0};
    half8 afrag[2];
#pragma unroll
    for (int mt = 0; mt < 2; mt++) {
        half8 a = *(const half8*)&qhl[(mbase + mt * 16 + l15) * ND];
        afrag[mt] = quad ? hz : a;      // k>=8 slots must be zero (B there is garbage)
    }
    const int vrow = (l15 == 8) ? 8 : (l15 & 7);
    const unsigned short* vbase = &vT[vrow * VSTRIDE];
    const int* mrow = mask + b * NS;
    unsigned int* Pw0 = Pu + wave * (2 * 16 * PSTRIDE);
    unsigned int* Pw1 = Pw0 + 16 * PSTRIDE;

    f32x4 O0 = {0.f, 0.f, 0.f, 0.f}, O1 = {0.f, 0.f, 0.f, 0.f};
    for (int ch = 0; ch < 64; ch++) {
        int tb = ch * 32;
        half8 bf0 = *(const half8*)&qhl[(tb + l15) * ND];
        half8 bf1 = *(const half8*)&qhl[(tb + 16 + l15) * ND];
        half8 vf = *(const half8*)&vbase[tb + quad * 8];
        float bias0 = mrow[tb + l15] ? 0.f : -30000.f;
        float bias1 = mrow[tb + 16 + l15] ? 0.f : -30000.f;
        f32x4 B0 = {bias0, bias0, bias0, bias0};
        f32x4 B1 = {bias1, bias1, bias1, bias1};

        f32x4 c0 = __builtin_amdgcn_mfma_f32_16x16x32_f16(afrag[0], bf0, B0, 0, 0, 0);
        f32x4 c1 = __builtin_amdgcn_mfma_f32_16x16x32_f16(afrag[0], bf1, B1, 0, 0, 0);
        f32x4 d0 = __builtin_amdgcn_mfma_f32_16x16x32_f16(afrag[1], bf0, B0, 0, 0, 0);
        f32x4 d1 = __builtin_amdgcn_mfma_f32_16x16x32_f16(afrag[1], bf1, B1, 0, 0, 0);
#pragma unroll
        for (int r = 0; r < 4; r++) {
            float e0 = __builtin_amdgcn_exp2f(c0[r]);
            float e1 = __builtin_amdgcn_exp2f(c1[r]);
            Pw0[(quad * 4 + r) * PSTRIDE + l15] = pkrtz(e0, e1);
            float f0 = __builtin_amdgcn_exp2f(d0[r]);
            float f1 = __builtin_amdgcn_exp2f(d1[r]);
            Pw1[(quad * 4 + r) * PSTRIDE + l15] = pkrtz(f0, f1);
        }
        __asm__ volatile("" ::: "memory");   // pin P writes before P reads
        half8 pf0 = ld_p(Pw0 + l15 * PSTRIDE + quad * 4);
        half8 pf1 = ld_p(Pw1 + l15 * PSTRIDE + quad * 4);
        O0 = __builtin_amdgcn_mfma_f32_16x16x32_f16(pf0, vf, O0, 0, 0, 0);
        O1 = __builtin_amdgcn_mfma_f32_16x16x32_f16(pf1, vf, O1, 0, 0, 0);
        __asm__ volatile("" ::: "memory");   // keep next iter's writes after reads
    }

    // ---- epilogue: l = column 8 of O; normalize; f16 store ----
#pragma unroll
    for (int mt = 0; mt < 2; mt++) {
        f32x4 O = mt ? O1 : O0;
#pragma unroll
        for (int r = 0; r < 4; r++) {
            float lsum = __shfl(O[r], (lane & 48) | 8, 64);
            float v = O[r] / lsum;
            if (l15 < ND) {
                int m = mbase + mt * 16 + quad * 4 + r;
                mid[(size_t)(b * NS + m) * NE + h * ND + l15] = f2h(v);
            }
        }
    }
}

// out = mid(f16) @ w^T, f16 MFMA. Block: 32 m-rows x full N=128; 4 waves.
// w converted to f16 in-LDS per block. grid = 256.
__global__ __launch_bounds__(256) void proj_kernel(
        const unsigned short* __restrict__ mid,
        const float* __restrict__ w,
        float* __restrict__ out) {
    __shared__ unsigned short wf[NE * 136];   // 34816 B (+8 pad: banks n*4, 2-way max)
    __shared__ unsigned short am[32 * 136];   // 8704 B
    const int rb = blockIdx.x * 32;
    const int tid = threadIdx.x;

    for (int i = tid; i < 2048; i += 256) {   // wf[n][k] = f16(w[n][k])
        const float* wp = w + i * 8;
        float4 a = *(const float4*)wp, c = *(const float4*)(wp + 4);
        uint4 pk;
        pk.x = pkrtz(a.x, a.y); pk.y = pkrtz(a.z, a.w);
        pk.z = pkrtz(c.x, c.y); pk.w = pkrtz(c.z, c.w);
        int n = i >> 4, k8 = (i & 15) * 8;
        *(uint4*)&wf[n * 136 + k8] = pk;
    }
    for (int i = tid; i < 512; i += 256) {    // am[r][k] = mid[rb+r][k]
        int r = i >> 4, k8 = (i & 15) * 8;
        uint4 v = *(const uint4*)&mid[(size_t)(rb + r) * NE + k8];
        *(uint4*)&am[r * 136 + k8] = v;
    }
    __syncthreads();

    const int wave = tid >> 6, lane = tid & 63;
    const int quad = lane >> 4, l15 = lane & 15;
    const int mt = wave & 1, nh = wave >> 1;  // wave: 16 m-rows x 64 n-cols

    half8 af[4];
#pragma unroll
    for (int kt = 0; kt < 4; kt++)
        af[kt] = *(const half8*)&am[(mt * 16 + l15) * 136 + kt * 32 + quad * 8];

#pragma unroll
    for (int nt = 0; nt < 4; nt++) {
        int n0 = (nh * 4 + nt) * 16;
        f32x4 acc = {0.f, 0.f, 0.f, 0.f};
#pragma unroll
        for (int kt = 0; kt < 4; kt++) {
            half8 bf = *(const half8*)&wf[(n0 + l15) * 136 + kt * 32 + quad * 8];
            acc = __builtin_amdgcn_mfma_f32_16x16x32_f16(af[kt], bf, acc, 0, 0, 0);
        }
#pragma unroll
        for (int r = 0; r < 4; r++)
            out[(size_t)(rb + mt * 16 + quad * 4 + r) * NE + n0 + l15] = acc[r];
    }
}

extern "C" void kernel_launch(void* const* d_in, const int* in_sizes, int n_in,
                              void* d_out, int out_size, void* d_ws, size_t ws_size,
                              hipStream_t stream) {
    const float* x     = (const float*)d_in[0];
    const float* theta = (const float*)d_in[1];
    const float* w_out = (const float*)d_in[2];
    const int*   mask  = (const int*)d_in[3];
    float* out = (float*)d_out;

    unsigned short* mid16 = (unsigned short*)d_ws;   // [B*S][NE] f16 = 2 MB (ws >= 4 MB proven in R3)

    attn_kernel<<<NB * NH * 4, 1024, 0, stream>>>(x, theta, mask, mid16);
    proj_kernel<<<NB * NS / 32, 256, 0, stream>>>(mid16, w_out, out);
}

// Round 8
// 110.878 us; speedup vs baseline: 2.6380x; 1.0174x over previous
//
#include <hip/hip_runtime.h>
#include <hip/hip_bf16.h>
#include <hip/hip_fp16.h>

#define NB 4
#define NS 2048
#define NE 128
#define NH 16
#define ND 8

typedef __attribute__((ext_vector_type(8))) _Float16 half8;
typedef __attribute__((ext_vector_type(4))) float f32x4;

#define VSTRIDE 2056   // shorts per vT row (multiple of 8 -> 16B-aligned b128 reads)

__device__ __forceinline__ unsigned int pkrtz(float a, float b) {
    typedef __fp16 fp16v2 __attribute__((ext_vector_type(2)));
    union { fp16v2 h; unsigned int u; } v;
    v.h = __builtin_amdgcn_cvt_pkrtz(a, b);
    return v.u;
}
__device__ __forceinline__ unsigned short f2h(float a) {
    return __half_as_ushort(__float2half(a));   // RNE
}
__device__ __forceinline__ half8 mk_half8(unsigned u0, unsigned u1,
                                          unsigned u2, unsigned u3) {
    union { half8 h; unsigned u[4]; } v;
    v.u[0] = u0; v.u[1] = u1; v.u[2] = u2; v.u[3] = u3;
    return v.h;
}

// One block = one (b,h) x one quarter of query rows (512). 1024 thr = 16
// waves, each wave 2 m-tiles of 16 rows; flash loop over 64 chunks of 32 t.
//
// TRANSPOSE-FREE pipeline: scores are computed as S^T via
// mfma(A = q_t-rows, B = q_m-rows, C = mask-bias). The C-layout of S^T gives
// each lane P[m=l15][t = tb+4*quad+r] — m fixed per lane — which under the
// k-permutation pi(8q+j) = 4q + (j&3) + 16*(j>>2) IS a valid A-operand for
// the PV MFMA. V^T is staged with rows pi-reordered, so the PV A-frag is
// built from 4 in-lane pkrtz of exp2(S^T) regs. No LDS P roundtrip at all.
// q scaled by SC = sqrt(log2e/sqrt(8)) -> exp2 directly; V^T ones-row at
// n=8 yields the softmax denominator as O column 8.
__global__ __launch_bounds__(1024) void attn_kernel(
        const float* __restrict__ x,
        const float* __restrict__ theta,
        const int* __restrict__ mask,
        unsigned short* __restrict__ mid) {            // f16 [B*S][NE]
    __shared__ unsigned short qhl[NS * ND + 24];       // 32816 B (+24: A-frag quad>0 overreads)
    __shared__ unsigned short vT[9 * VSTRIDE];         // 37008 B: pi-ordered V^T + ones row

    const int bid = blockIdx.x;
    const int bh = bid >> 2;
    const int b = bh >> 4, h = bh & (NH - 1);
    const int mquart = bid & 3;
    const int tid = threadIdx.x;

    const float SC = 0.71421629f;   // sqrt(log2(e)/sqrt(8))

    float th[ND];
#pragma unroll
    for (int d = 0; d < ND; d++) th[d] = theta[d];

    // ---- stage: thread handles the pi-pair rows r0 = tb+ta, r1 = r0+1 ----
    {
        int chs = tid >> 4, i = tid & 15;
        int ta = 4 * (i >> 2) + 2 * (i & 1) + 16 * ((i >> 1) & 1);
        int r0 = chs * 32 + ta, r1 = r0 + 1;
        float p0[ND], p1[ND];
        {
            const float* xp = x + ((size_t)(b * NS + r0) * NE + h * ND);
            float4 a = *(const float4*)xp, c = *(const float4*)(xp + 4);
            float p = 1.f;
            p *= cosf(a.x + th[0]); p0[0] = p; p *= cosf(a.y + th[1]); p0[1] = p;
            p *= cosf(a.z + th[2]); p0[2] = p; p *= cosf(a.w + th[3]); p0[3] = p;
            p *= cosf(c.x + th[4]); p0[4] = p; p *= cosf(c.y + th[5]); p0[5] = p;
            p *= cosf(c.z + th[6]); p0[6] = p; p *= cosf(c.w + th[7]); p0[7] = p;
        }
        {
            const float* xp = x + ((size_t)(b * NS + r1) * NE + h * ND);
            float4 a = *(const float4*)xp, c = *(const float4*)(xp + 4);
            float p = 1.f;
            p *= cosf(a.x + th[0]); p1[0] = p; p *= cosf(a.y + th[1]); p1[1] = p;
            p *= cosf(a.z + th[2]); p1[2] = p; p *= cosf(a.w + th[3]); p1[3] = p;
            p *= cosf(c.x + th[4]); p1[4] = p; p *= cosf(c.y + th[5]); p1[5] = p;
            p *= cosf(c.z + th[6]); p1[6] = p; p *= cosf(c.w + th[7]); p1[7] = p;
        }
        uint4 qa, qb;
        qa.x = pkrtz(p0[0] * SC, p0[1] * SC);
        qa.y = pkrtz(p0[2] * SC, p0[3] * SC);
        qa.z = pkrtz(p0[4] * SC, p0[5] * SC);
        qa.w = pkrtz(p0[6] * SC, p0[7] * SC);
        qb.x = pkrtz(p1[0] * SC, p1[1] * SC);
        qb.y = pkrtz(p1[2] * SC, p1[3] * SC);
        qb.z = pkrtz(p1[4] * SC, p1[5] * SC);
        qb.w = pkrtz(p1[6] * SC, p1[7] * SC);
        *(uint4*)&qhl[r0 * ND] = qa;
        *(uint4*)&qhl[r1 * ND] = qb;
        // pi-ordered V^T: uint slot i of chunk chs = (V[r0][d], V[r1][d])
#pragma unroll
        for (int d = 0; d < ND; d++)
            *(unsigned int*)&vT[d * VSTRIDE + chs * 32 + 2 * i] = pkrtz(p0[d], p1[d]);
        *(unsigned int*)&vT[8 * VSTRIDE + chs * 32 + 2 * i] = 0x3C003C00u;  // ones
    }
    if (tid < 24) qhl[NS * ND + tid] = 0;   // pad (values never used: B k>=8 is zero)
    __syncthreads();

    // ---- main loop ----
    const int wave = tid >> 6, lane = tid & 63;
    const int quad = lane >> 4, l15 = lane & 15;
    const int mbase = mquart * 512 + wave * 32;

    half8 hz = {0, 0, 0, 0, 0, 0, 0, 0};
    // B operand (q_m): lane l15 = m-col; quad 0 holds real k=0..7, rest zero.
    half8 bm0 = quad ? hz : *(const half8*)&qhl[(mbase + l15) * ND];
    half8 bm1 = quad ? hz : *(const half8*)&qhl[(mbase + 16 + l15) * ND];

    const int vrow = (l15 < 9) ? l15 : 8;
    const unsigned short* vbase = &vT[vrow * VSTRIDE];
    const int* mrow = mask + b * NS;

    f32x4 O0 = {0.f, 0.f, 0.f, 0.f}, O1 = {0.f, 0.f, 0.f, 0.f};
    for (int ch = 0; ch < 64; ch++) {
        int tb = ch * 32;
        // A operand (q_t): quad>0 slots read neighbor rows (garbage) — zeroed by B.
        half8 at0 = *(const half8*)&qhl[(tb + l15) * ND + quad * 8];
        half8 at1 = *(const half8*)&qhl[(tb + 16 + l15) * ND + quad * 8];
        half8 vf  = *(const half8*)&vbase[tb + quad * 8];
        int4 mk0 = *(const int4*)&mrow[tb + quad * 4];
        int4 mk1 = *(const int4*)&mrow[tb + 16 + quad * 4];
        f32x4 C0 = {mk0.x ? 0.f : -30000.f, mk0.y ? 0.f : -30000.f,
                    mk0.z ? 0.f : -30000.f, mk0.w ? 0.f : -30000.f};
        f32x4 C1 = {mk1.x ? 0.f : -30000.f, mk1.y ? 0.f : -30000.f,
                    mk1.z ? 0.f : -30000.f, mk1.w ? 0.f : -30000.f};

        // S^T tiles: rows t = tb(+16) + quad*4 + r, cols m = l15
        f32x4 s00 = __builtin_amdgcn_mfma_f32_16x16x32_f16(at0, bm0, C0, 0, 0, 0);
        f32x4 s01 = __builtin_amdgcn_mfma_f32_16x16x32_f16(at0, bm1, C0, 0, 0, 0);
        f32x4 s10 = __builtin_amdgcn_mfma_f32_16x16x32_f16(at1, bm0, C1, 0, 0, 0);
        f32x4 s11 = __builtin_amdgcn_mfma_f32_16x16x32_f16(at1, bm1, C1, 0, 0, 0);

        // exp2 + in-lane pack -> PV A-frags (k-order = pi)
        half8 pA0 = mk_half8(
            pkrtz(__builtin_amdgcn_exp2f(s00[0]), __builtin_amdgcn_exp2f(s00[1])),
            pkrtz(__builtin_amdgcn_exp2f(s00[2]), __builtin_amdgcn_exp2f(s00[3])),
            pkrtz(__builtin_amdgcn_exp2f(s10[0]), __builtin_amdgcn_exp2f(s10[1])),
            pkrtz(__builtin_amdgcn_exp2f(s10[2]), __builtin_amdgcn_exp2f(s10[3])));
        half8 pA1 = mk_half8(
            pkrtz(__builtin_amdgcn_exp2f(s01[0]), __builtin_amdgcn_exp2f(s01[1])),
            pkrtz(__builtin_amdgcn_exp2f(s01[2]), __builtin_amdgcn_exp2f(s01[3])),
            pkrtz(__builtin_amdgcn_exp2f(s11[0]), __builtin_amdgcn_exp2f(s11[1])),
            pkrtz(__builtin_amdgcn_exp2f(s11[2]), __builtin_amdgcn_exp2f(s11[3])));

        O0 = __builtin_amdgcn_mfma_f32_16x16x32_f16(pA0, vf, O0, 0, 0, 0);
        O1 = __builtin_amdgcn_mfma_f32_16x16x32_f16(pA1, vf, O1, 0, 0, 0);
    }

    // ---- epilogue: l = column 8 of O; normalize; f16 store ----
#pragma unroll
    for (int mt = 0; mt < 2; mt++) {
        f32x4 O = mt ? O1 : O0;
#pragma unroll
        for (int r = 0; r < 4; r++) {
            float lsum = __shfl(O[r], (lane & 48) | 8, 64);
            float v = O[r] / lsum;
            if (l15 < ND) {
                int m = mbase + mt * 16 + quad * 4 + r;
                mid[(size_t)(b * NS + m) * NE + h * ND + l15] = f2h(v);
            }
        }
    }
}

// out = mid(f16) @ w^T, f16 MFMA. Block: 32 m-rows x full N=128; 4 waves.
__global__ __launch_bounds__(256) void proj_kernel(
        const unsigned short* __restrict__ mid,
        const float* __restrict__ w,
        float* __restrict__ out) {
    __shared__ unsigned short wf[NE * 136];
    __shared__ unsigned short am[32 * 136];
    const int rb = blockIdx.x * 32;
    const int tid = threadIdx.x;

    for (int i = tid; i < 2048; i += 256) {   // wf[n][k] = f16(w[n][k])
        const float* wp = w + i * 8;
        float4 a = *(const float4*)wp, c = *(const float4*)(wp + 4);
        uint4 pk;
        pk.x = pkrtz(a.x, a.y); pk.y = pkrtz(a.z, a.w);
        pk.z = pkrtz(c.x, c.y); pk.w = pkrtz(c.z, c.w);
        int n = i >> 4, k8 = (i & 15) * 8;
        *(uint4*)&wf[n * 136 + k8] = pk;
    }
    for (int i = tid; i < 512; i += 256) {    // am[r][k] = mid[rb+r][k]
        int r = i >> 4, k8 = (i & 15) * 8;
        uint4 v = *(const uint4*)&mid[(size_t)(rb + r) * NE + k8];
        *(uint4*)&am[r * 136 + k8] = v;
    }
    __syncthreads();

    const int wave = tid >> 6, lane = tid & 63;
    const int quad = lane >> 4, l15 = lane & 15;
    const int mt = wave & 1, nh = wave >> 1;

    half8 af[4];
#pragma unroll
    for (int kt = 0; kt < 4; kt++)
        af[kt] = *(const half8*)&am[(mt * 16 + l15) * 136 + kt * 32 + quad * 8];

#pragma unroll
    for (int nt = 0; nt < 4; nt++) {
        int n0 = (nh * 4 + nt) * 16;
        f32x4 acc = {0.f, 0.f, 0.f, 0.f};
#pragma unroll
        for (int kt = 0; kt < 4; kt++) {
            half8 bf = *(const half8*)&wf[(n0 + l15) * 136 + kt * 32 + quad * 8];
            acc = __builtin_amdgcn_mfma_f32_16x16x32_f16(af[kt], bf, acc, 0, 0, 0);
        }
#pragma unroll
        for (int r = 0; r < 4; r++)
            out[(size_t)(rb + mt * 16 + quad * 4 + r) * NE + n0 + l15] = acc[r];
    }
}

extern "C" void kernel_launch(void* const* d_in, const int* in_sizes, int n_in,
                              void* d_out, int out_size, void* d_ws, size_t ws_size,
                              hipStream_t stream) {
    const float* x     = (const float*)d_in[0];
    const float* theta = (const float*)d_in[1];
    const float* w_out = (const float*)d_in[2];
    const int*   mask  = (const int*)d_in[3];
    float* out = (float*)d_out;

    unsigned short* mid16 = (unsigned short*)d_ws;   // f16 [B*S][NE] = 2 MB

    attn_kernel<<<NB * NH * 4, 1024, 0, stream>>>(x, theta, mask, mid16);
    proj_kernel<<<NB * NS / 32, 256, 0, stream>>>(mid16, w_out, out);
}

// Round 9
// 102.739 us; speedup vs baseline: 2.8470x; 1.0792x over previous
//
#include <hip/hip_runtime.h>
#include <hip/hip_bf16.h>
#include <hip/hip_fp16.h>

#define NB 4
#define NS 2048
#define NE 128
#define NH 16
#define ND 8

typedef __attribute__((ext_vector_type(8))) _Float16 half8;
typedef __attribute__((ext_vector_type(4))) float f32x4;

#define VSTRIDE 2056   // shorts per vT row (multiple of 8 -> 16B-aligned b128 reads)

__device__ __forceinline__ unsigned int pkrtz(float a, float b) {
    typedef __fp16 fp16v2 __attribute__((ext_vector_type(2)));
    union { fp16v2 h; unsigned int u; } v;
    v.h = __builtin_amdgcn_cvt_pkrtz(a, b);
    return v.u;
}
__device__ __forceinline__ unsigned short f2h(float a) {
    return __half_as_ushort(__float2half(a));   // RNE
}
__device__ __forceinline__ half8 mk_half8(unsigned u0, unsigned u1,
                                          unsigned u2, unsigned u3) {
    union { half8 h; unsigned u[4]; } v;
    v.u[0] = u0; v.u[1] = u1; v.u[2] = u2; v.u[3] = u3;
    return v.h;
}

// One block = one (b,h) x one EIGHTH of query rows (256). 512 thr = 8 waves,
// each wave 2 m-tiles of 16 rows; flash loop over 64 chunks of 32 t.
// 78 KB LDS -> 2 blocks/CU -> 8 waves/SIMD (R8 had 4: latency-fill was the
// bottleneck, VALUBusy 53%).
//
// TRANSPOSE-FREE pipeline (verified R8): scores computed as S^T via
// mfma(A = q_t-rows, B = q_m-rows, C = mask-bias-from-LDS). C-layout of S^T
// gives each lane P[m=l15][t=tb+4*quad+r] — already A-operand-shaped for the
// PV MFMA under k-permutation pi(8q+j) = 4q + (j&3) + 16*(j>>2); V^T rows are
// staged pi-reordered. PV A-frag = 4 in-lane pkrtz of exp2(S^T). q scaled by
// SC = sqrt(log2e/sqrt(8)) -> exp2 directly; V^T ones-row at n=8 yields the
// softmax denominator as O column 8.
__global__ __launch_bounds__(512) void attn_kernel(
        const float* __restrict__ x,
        const float* __restrict__ theta,
        const int* __restrict__ mask,
        unsigned short* __restrict__ mid) {            // f16 [B*S][NE]
    __shared__ unsigned short qhl[NS * ND + 24];       // 32,816 B (+24: A-frag overread pad)
    __shared__ unsigned short vT[9 * VSTRIDE];         // 37,008 B: pi-ordered V^T + ones row
    __shared__ float kb[NS];                           //  8,192 B: 0 / -30000 bias

    const int bid = blockIdx.x;
    const int bh = bid >> 3;
    const int b = bh >> 4, h = bh & (NH - 1);
    const int meighth = bid & 7;
    const int tid = threadIdx.x;

    const float SC = 0.71421629f;   // sqrt(log2(e)/sqrt(8))

    float th[ND];
#pragma unroll
    for (int d = 0; d < ND; d++) th[d] = theta[d];

    // ---- stage q + pi-ordered V^T: 2 pi-pairs per thread ----
    for (int idx = tid; idx < 1024; idx += 512) {
        int chs = idx >> 4, i = idx & 15;
        int ta = 4 * (i >> 2) + 2 * (i & 1) + 16 * ((i >> 1) & 1);
        int r0 = chs * 32 + ta, r1 = r0 + 1;
        float p0[ND], p1[ND];
        {
            const float* xp = x + ((size_t)(b * NS + r0) * NE + h * ND);
            float4 a = *(const float4*)xp, c = *(const float4*)(xp + 4);
            float p = 1.f;
            p *= cosf(a.x + th[0]); p0[0] = p; p *= cosf(a.y + th[1]); p0[1] = p;
            p *= cosf(a.z + th[2]); p0[2] = p; p *= cosf(a.w + th[3]); p0[3] = p;
            p *= cosf(c.x + th[4]); p0[4] = p; p *= cosf(c.y + th[5]); p0[5] = p;
            p *= cosf(c.z + th[6]); p0[6] = p; p *= cosf(c.w + th[7]); p0[7] = p;
        }
        {
            const float* xp = x + ((size_t)(b * NS + r1) * NE + h * ND);
            float4 a = *(const float4*)xp, c = *(const float4*)(xp + 4);
            float p = 1.f;
            p *= cosf(a.x + th[0]); p1[0] = p; p *= cosf(a.y + th[1]); p1[1] = p;
            p *= cosf(a.z + th[2]); p1[2] = p; p *= cosf(a.w + th[3]); p1[3] = p;
            p *= cosf(c.x + th[4]); p1[4] = p; p *= cosf(c.y + th[5]); p1[5] = p;
            p *= cosf(c.z + th[6]); p1[6] = p; p *= cosf(c.w + th[7]); p1[7] = p;
        }
        uint4 qa, qb;
        qa.x = pkrtz(p0[0] * SC, p0[1] * SC);
        qa.y = pkrtz(p0[2] * SC, p0[3] * SC);
        qa.z = pkrtz(p0[4] * SC, p0[5] * SC);
        qa.w = pkrtz(p0[6] * SC, p0[7] * SC);
        qb.x = pkrtz(p1[0] * SC, p1[1] * SC);
        qb.y = pkrtz(p1[2] * SC, p1[3] * SC);
        qb.z = pkrtz(p1[4] * SC, p1[5] * SC);
        qb.w = pkrtz(p1[6] * SC, p1[7] * SC);
        *(uint4*)&qhl[r0 * ND] = qa;
        *(uint4*)&qhl[r1 * ND] = qb;
#pragma unroll
        for (int d = 0; d < ND; d++)
            *(unsigned int*)&vT[d * VSTRIDE + chs * 32 + 2 * i] = pkrtz(p0[d], p1[d]);
        *(unsigned int*)&vT[8 * VSTRIDE + chs * 32 + 2 * i] = 0x3C003C00u;  // ones
    }
    for (int i = tid; i < NS; i += 512)
        kb[i] = mask[b * NS + i] ? 0.f : -30000.f;
    if (tid < 24) qhl[NS * ND + tid] = 0;   // pad (never contributes: B k>=8 is zero)
    __syncthreads();

    // ---- main loop ----
    const int wave = tid >> 6, lane = tid & 63;
    const int quad = lane >> 4, l15 = lane & 15;
    const int mbase = meighth * 256 + wave * 32;

    half8 hz = {0, 0, 0, 0, 0, 0, 0, 0};
    // B operand (q_m): lane l15 = m-col; quad 0 holds real k=0..7, rest zero.
    half8 bm0 = quad ? hz : *(const half8*)&qhl[(mbase + l15) * ND];
    half8 bm1 = quad ? hz : *(const half8*)&qhl[(mbase + 16 + l15) * ND];

    const int vrow = (l15 < 9) ? l15 : 8;
    const unsigned short* vbase = &vT[vrow * VSTRIDE];

    f32x4 O0 = {0.f, 0.f, 0.f, 0.f}, O1 = {0.f, 0.f, 0.f, 0.f};
    for (int ch = 0; ch < 64; ch++) {
        int tb = ch * 32;
        // A operand (q_t): quad>0 slots read neighbor rows (garbage) — zeroed by B.
        half8 at0 = *(const half8*)&qhl[(tb + l15) * ND + quad * 8];
        half8 at1 = *(const half8*)&qhl[(tb + 16 + l15) * ND + quad * 8];
        half8 vf  = *(const half8*)&vbase[tb + quad * 8];
        // bias rows t = tb(+16) + quad*4 + r — quad-uniform b128 broadcast
        f32x4 C0 = *(const f32x4*)&kb[tb + quad * 4];
        f32x4 C1 = *(const f32x4*)&kb[tb + 16 + quad * 4];

        // S^T tiles: rows t, cols m = l15
        f32x4 s00 = __builtin_amdgcn_mfma_f32_16x16x32_f16(at0, bm0, C0, 0, 0, 0);
        f32x4 s01 = __builtin_amdgcn_mfma_f32_16x16x32_f16(at0, bm1, C0, 0, 0, 0);
        f32x4 s10 = __builtin_amdgcn_mfma_f32_16x16x32_f16(at1, bm0, C1, 0, 0, 0);
        f32x4 s11 = __builtin_amdgcn_mfma_f32_16x16x32_f16(at1, bm1, C1, 0, 0, 0);

        // exp2 + in-lane pack -> PV A-frags (k-order = pi)
        half8 pA0 = mk_half8(
            pkrtz(__builtin_amdgcn_exp2f(s00[0]), __builtin_amdgcn_exp2f(s00[1])),
            pkrtz(__builtin_amdgcn_exp2f(s00[2]), __builtin_amdgcn_exp2f(s00[3])),
            pkrtz(__builtin_amdgcn_exp2f(s10[0]), __builtin_amdgcn_exp2f(s10[1])),
            pkrtz(__builtin_amdgcn_exp2f(s10[2]), __builtin_amdgcn_exp2f(s10[3])));
        half8 pA1 = mk_half8(
            pkrtz(__builtin_amdgcn_exp2f(s01[0]), __builtin_amdgcn_exp2f(s01[1])),
            pkrtz(__builtin_amdgcn_exp2f(s01[2]), __builtin_amdgcn_exp2f(s01[3])),
            pkrtz(__builtin_amdgcn_exp2f(s11[0]), __builtin_amdgcn_exp2f(s11[1])),
            pkrtz(__builtin_amdgcn_exp2f(s11[2]), __builtin_amdgcn_exp2f(s11[3])));

        O0 = __builtin_amdgcn_mfma_f32_16x16x32_f16(pA0, vf, O0, 0, 0, 0);
        O1 = __builtin_amdgcn_mfma_f32_16x16x32_f16(pA1, vf, O1, 0, 0, 0);
    }

    // ---- epilogue: l = column 8 of O; normalize; f16 store ----
#pragma unroll
    for (int mt = 0; mt < 2; mt++) {
        f32x4 O = mt ? O1 : O0;
#pragma unroll
        for (int r = 0; r < 4; r++) {
            float lsum = __shfl(O[r], (lane & 48) | 8, 64);
            float v = O[r] / lsum;
            if (l15 < ND) {
                int m = mbase + mt * 16 + quad * 4 + r;
                mid[(size_t)(b * NS + m) * NE + h * ND + l15] = f2h(v);
            }
        }
    }
}

// out = mid(f16) @ w^T, f16 MFMA. Block: 32 m-rows x full N=128; 4 waves.
__global__ __launch_bounds__(256) void proj_kernel(
        const unsigned short* __restrict__ mid,
        const float* __restrict__ w,
        float* __restrict__ out) {
    __shared__ unsigned short wf[NE * 136];
    __shared__ unsigned short am[32 * 136];
    const int rb = blockIdx.x * 32;
    const int tid = threadIdx.x;

    for (int i = tid; i < 2048; i += 256) {   // wf[n][k] = f16(w[n][k])
        const float* wp = w + i * 8;
        float4 a = *(const float4*)wp, c = *(const float4*)(wp + 4);
        uint4 pk;
        pk.x = pkrtz(a.x, a.y); pk.y = pkrtz(a.z, a.w);
        pk.z = pkrtz(c.x, c.y); pk.w = pkrtz(c.z, c.w);
        int n = i >> 4, k8 = (i & 15) * 8;
        *(uint4*)&wf[n * 136 + k8] = pk;
    }
    for (int i = tid; i < 512; i += 256) {    // am[r][k] = mid[rb+r][k]
        int r = i >> 4, k8 = (i & 15) * 8;
        uint4 v = *(const uint4*)&mid[(size_t)(rb + r) * NE + k8];
        *(uint4*)&am[r * 136 + k8] = v;
    }
    __syncthreads();

    const int wave = tid >> 6, lane = tid & 63;
    const int quad = lane >> 4, l15 = lane & 15;
    const int mt = wave & 1, nh = wave >> 1;

    half8 af[4];
#pragma unroll
    for (int kt = 0; kt < 4; kt++)
        af[kt] = *(const half8*)&am[(mt * 16 + l15) * 136 + kt * 32 + quad * 8];

#pragma unroll
    for (int nt = 0; nt < 4; nt++) {
        int n0 = (nh * 4 + nt) * 16;
        f32x4 acc = {0.f, 0.f, 0.f, 0.f};
#pragma unroll
        for (int kt = 0; kt < 4; kt++) {
            half8 bf = *(const half8*)&wf[(n0 + l15) * 136 + kt * 32 + quad * 8];
            acc = __builtin_amdgcn_mfma_f32_16x16x32_f16(af[kt], bf, acc, 0, 0, 0);
        }
#pragma unroll
        for (int r = 0; r < 4; r++)
            out[(size_t)(rb + mt * 16 + quad * 4 + r) * NE + n0 + l15] = acc[r];
    }
}

extern "C" void kernel_launch(void* const* d_in, const int* in_sizes, int n_in,
                              void* d_out, int out_size, void* d_ws, size_t ws_size,
                              hipStream_t stream) {
    const float* x     = (const float*)d_in[0];
    const float* theta = (const float*)d_in[1];
    const float* w_out = (const float*)d_in[2];
    const int*   mask  = (const int*)d_in[3];
    float* out = (float*)d_out;

    unsigned short* mid16 = (unsigned short*)d_ws;   // f16 [B*S][NE] = 2 MB

    attn_kernel<<<NB * NH * 8, 512, 0, stream>>>(x, theta, mask, mid16);
    proj_kernel<<<NB * NS / 32, 256, 0, stream>>>(mid16, w_out, out);
}